// Round 2
// baseline (140.966 us; speedup 1.0000x reference)
//
#include <hip/hip_runtime.h>

#define S_ 512
#define L_ 128
#define D_ 256
#define V_ 50000
#define EV_ 10000
#define ED_ 64
#define B_ 128
#define P_ 16
#define H2_ 128
#define F_ 256
#define FEAT_ 640
#define SH_STRIDE 264  // D_ + 8 pad: 16B-aligned rows, spreads p-rows across banks

// One block per (b, pool) pair. pool 0 = spos, 1 = tpos.
__global__ __launch_bounds__(256) void pool_kernel(
    const int* __restrict__ x, const int* __restrict__ spos, const int* __restrict__ tpos,
    const float* __restrict__ emb,
    const float* __restrict__ attw_W, const float* __restrict__ attw_b,
    const float* __restrict__ attw2_W,
    float* __restrict__ ws_pool)
{
    const int bid = blockIdx.x;
    const int b = bid >> 1, pool = bid & 1;
    const int t = threadIdx.x;

    __shared__ float sh[P_ * SH_STRIDE];   // gathered h rows, fp32
    __shared__ float part[P_ * 256];       // partial dots: [p][h*2+dh]
    __shared__ float wsum[4][8];
    __shared__ float wts[P_];

    // ---- gather: 16 threads per row, 16 floats (4 x float4) each ----
    {
        const int* pos = pool ? tpos : spos;
        const int p = t >> 4, i = t & 15;
        const int si  = pos[(b * P_ + p) * 2 + 0];
        const int ti  = pos[(b * P_ + p) * 2 + 1];
        const int tok = x[si * L_ + ti];
        const float4* row = (const float4*)(emb + (size_t)tok * D_);  // 64 float4
        float* dst = &sh[p * SH_STRIDE + i * 16];
        #pragma unroll
        for (int j = 0; j < 4; ++j) {
            float4 v = row[i * 4 + j];
            dst[j * 4 + 0] = v.x; dst[j * 4 + 1] = v.y;
            dst[j * 4 + 2] = v.z; dst[j * 4 + 3] = v.w;
        }
    }
    __syncthreads();

    // ---- energy partial dots: thread = (h = t>>1, d-half = t&1), 16 p-accumulators ----
    {
        const int h = t >> 1, dh = t & 1;
        const int d0 = dh * 128;
        const float4* awrow = (const float4*)(attw_W + (size_t)h * D_ + d0); // 32 float4
        float acc[P_];
        #pragma unroll
        for (int p = 0; p < P_; ++p) acc[p] = 0.f;
        float4 nxt = awrow[0];
        for (int c = 0; c < 32; ++c) {
            float4 a = nxt;
            if (c < 31) nxt = awrow[c + 1];   // 1-deep prefetch hides L2 latency
            const int d = d0 + c * 4;
            #pragma unroll
            for (int p = 0; p < P_; ++p) {
                float4 s = *(const float4*)&sh[p * SH_STRIDE + d]; // 2-addr broadcast
                acc[p] += a.x * s.x + a.y * s.y + a.z * s.z + a.w * s.w;
            }
        }
        #pragma unroll
        for (int p = 0; p < P_; ++p) part[p * 256 + t] = acc[p];  // t == h*2+dh
    }
    __syncthreads();

    // ---- logits[p] = sum_h tanh(dot + b[h]) * attw2[h] ----
    {
        const int h = t & 127, pg = t >> 7;
        const float bias = attw_b[h];
        const float w2   = attw2_W[h];
        float v[8];
        #pragma unroll
        for (int k = 0; k < 8; ++k) {
            const int p = pg * 8 + k;
            float e = part[p * 256 + 2 * h] + part[p * 256 + 2 * h + 1] + bias;
            v[k] = tanhf(e) * w2;
        }
        #pragma unroll
        for (int k = 0; k < 8; ++k) {
            float s = v[k];
            for (int m = 32; m >= 1; m >>= 1) s += __shfl_xor(s, m, 64);
            v[k] = s;
        }
        const int wid = t >> 6;
        if ((t & 63) == 0) {
            #pragma unroll
            for (int k = 0; k < 8; ++k) wsum[wid][k] = v[k];
        }
    }
    __syncthreads();

    // ---- softmax over P=16 (threads 0..15, one p each) ----
    if (t < P_) {
        const int pg = t >> 3, k = t & 7;
        float l = wsum[pg * 2][k] + wsum[pg * 2 + 1][k];
        float m = l;
        for (int mm = 8; mm >= 1; mm >>= 1) m = fmaxf(m, __shfl_xor(m, mm, 16));
        float e = expf(l - m);
        float ssum = e;
        for (int mm = 8; mm >= 1; mm >>= 1) ssum += __shfl_xor(ssum, mm, 16);
        wts[t] = e / ssum;
    }
    __syncthreads();

    // ---- weighted pool, coalesced store: thread t = dimension d ----
    {
        float acc = 0.f;
        #pragma unroll
        for (int p = 0; p < P_; ++p) acc += wts[p] * sh[p * SH_STRIDE + t];
        ws_pool[(size_t)b * 512 + pool * 256 + t] = acc;
    }
}

// One block per b: feats -> condensed -> tanh -> linear head.
__global__ __launch_bounds__(256) void head_kernel(
    const int* __restrict__ ents,
    const float* __restrict__ ent_emb,
    const float* __restrict__ cond_W, const float* __restrict__ cond_b,
    const float* __restrict__ lin_W, const float* __restrict__ lin_b,
    const float* __restrict__ ws_pool,
    float* __restrict__ out)
{
    const int b = blockIdx.x, t = threadIdx.x;
    __shared__ float feats[FEAT_];
    __shared__ float r0[4], r1[4];

    feats[t]       = ws_pool[(size_t)b * 512 + t];
    feats[256 + t] = ws_pool[(size_t)b * 512 + 256 + t];
    if (t < 128) {
        const int e = ents[b * 2 + (t >> 6)];
        feats[512 + t] = ent_emb[(size_t)e * ED_ + (t & 63)];
    }
    __syncthreads();

    // condensed[f], f = t: 640-length dot; feats reads are full-wave broadcasts
    const float4* wrow = (const float4*)(cond_W + (size_t)t * FEAT_);  // 160 float4
    float acc = cond_b[t];
    float4 nxt = wrow[0];
    for (int c = 0; c < 160; ++c) {
        float4 a = nxt;
        if (c < 159) nxt = wrow[c + 1];
        const float* fp = &feats[c * 4];
        acc += a.x * fp[0] + a.y * fp[1] + a.z * fp[2] + a.w * fp[3];
    }
    const float tv = tanhf(acc);
    float v0 = tv * lin_W[t];
    float v1 = tv * lin_W[256 + t];
    for (int m = 32; m >= 1; m >>= 1) {
        v0 += __shfl_xor(v0, m, 64);
        v1 += __shfl_xor(v1, m, 64);
    }
    if ((t & 63) == 0) { r0[t >> 6] = v0; r1[t >> 6] = v1; }
    __syncthreads();
    if (t == 0) {
        out[b * 2 + 0] = r0[0] + r0[1] + r0[2] + r0[3] + lin_b[0];
        out[b * 2 + 1] = r1[0] + r1[1] + r1[2] + r1[3] + lin_b[1];
    }
}

extern "C" void kernel_launch(void* const* d_in, const int* in_sizes, int n_in,
                              void* d_out, int out_size, void* d_ws, size_t ws_size,
                              hipStream_t stream)
{
    const int* x     = (const int*)d_in[0];
    const int* ents  = (const int*)d_in[1];
    const int* spos  = (const int*)d_in[2];
    const int* tpos  = (const int*)d_in[3];
    const float* emb     = (const float*)d_in[4];
    const float* ent_emb = (const float*)d_in[5];
    const float* attw_W  = (const float*)d_in[6];
    const float* attw_b  = (const float*)d_in[7];
    const float* attw2_W = (const float*)d_in[8];
    const float* cond_W  = (const float*)d_in[9];
    const float* cond_b  = (const float*)d_in[10];
    const float* lin_W   = (const float*)d_in[11];
    const float* lin_b   = (const float*)d_in[12];
    float* ws_pool = (float*)d_ws;   // [B][2][D] fp32 = 256 KB
    float* out = (float*)d_out;      // [B][2] fp32

    pool_kernel<<<2 * B_, 256, 0, stream>>>(x, spos, tpos, emb, attw_W, attw_b, attw2_W, ws_pool);
    head_kernel<<<B_, 256, 0, stream>>>(ents, ent_emb, cond_W, cond_b, lin_W, lin_b, ws_pool, out);
}